// Round 12
// baseline (683.264 us; speedup 1.0000x reference)
//
#include <hip/hip_runtime.h>

#define N_NODES 50000
#define N_EDGES 800000
#define C_MSG 200

typedef __bf16 bf16;
typedef __attribute__((ext_vector_type(8))) __bf16 bf16x8;
typedef __attribute__((ext_vector_type(4))) float f32x4;

static __device__ __forceinline__ unsigned int pk_bf16(float a, float b) {
    union { bf16 h[2]; unsigned int u; } cv;
    cv.h[0] = (bf16)a; cv.h[1] = (bf16)b;
    return cv.u;
}

static __device__ __forceinline__ f32x4 MF(bf16x8 a, bf16x8 b, f32x4 c) {
    return __builtin_amdgcn_mfma_f32_16x16x32_bf16(a, b, c, 0, 0, 0);
}

// ===========================================================================
// Weight packers (device fns) -> MFMA B-frag order (16x16x32), biases folded.
// Fragment f at out[f*512 + lane*8 + i]; lane holds B[k][n], k=kt*32+(lane>>4)*8+i.
// Paired N-tiles: pair p covers cols p*32 + 2*(lane&15) + parity.
// ===========================================================================
static __device__ void dev_pack_wm1(int tid, const float* W, const float* bm1,
                                    bf16* out) {
    int i = tid & 7, lane = (tid >> 3) & 63, rest = tid >> 9;
    int kt = rest % 2, t = rest / 2;
    int k = kt * 32 + ((lane >> 4) * 8) + i;
    int c = lane & 15;
    int n = (t < 12) ? ((t >> 1) * 32 + 2 * c + (t & 1)) : (192 + c);
    float v = 0.f;
    if (n < C_MSG) {
        if (k < 30)       v = W[k * C_MSG + n];
        else if (k == 30) v = bm1[n];
        else if (k >= 32) v = W[(k - 2) * C_MSG + n];
    }
    out[tid] = (bf16)v;
}

static __device__ void dev_pack_wm2(int tid, const float* W, const float* bm2,
                                    bf16* out) {
    int i = tid & 7, lane = (tid >> 3) & 63, rest = tid >> 9;
    int kt = rest % 7, nt = rest / 7;
    int k = kt * 32 + ((lane >> 4) * 8) + i;
    int n = 2 * (lane & 15) + nt;
    float v = 0.f;
    if (n < 30) {
        if (k < C_MSG)       v = W[k * 30 + n];
        else if (k == C_MSG) v = bm2[n];
    }
    out[tid] = (bf16)v;
}

static __device__ void dev_pack_w2h(int tid, const float* W, const float* b2,
                                    bf16* out) {
    int i = tid & 7, lane = (tid >> 3) & 63, nt = tid >> 9;
    int k = ((lane >> 4) * 8) + i;
    int n = 2 * (lane & 15) + nt;
    float v = 0.f;
    if (n < 30) {
        if (k < 30)       v = W[k * 30 + n];
        else if (k == 30) v = b2[n];
    }
    out[tid] = (bf16)v;
}

static __device__ void dev_pack_w2o(int tid, const float* W, const float* b2,
                                    bf16* out) {
    int i = tid & 7, lane = (tid >> 3) & 63;
    int k = ((lane >> 4) * 8) + i;
    int n = lane & 15;
    float v = 0.f;
    if (n == 0) {
        if (k < 30)       v = W[k];
        else if (k == 30) v = b2[0];
    }
    out[tid] = (bf16)v;
}

static __device__ void dev_pack_sel(int tid, bf16* out) {
    int i = tid & 7, lane = (tid >> 3) & 63, f = tid >> 9;
    int kt = f >> 1, nt = f & 1;
    int kloc = ((lane >> 4) * 8) + i;
    int n = 2 * (lane & 15) + nt;
    float v = (kloc == n && n < 30) ? ((kt & 1) ? -1.f : 1.f) : 0.f;
    out[tid] = (bf16)v;
}

// ===========================================================================
// setup_a: count (3125 blocks) + pack_all (186) + node_d (196) in ONE dispatch
// ===========================================================================
__global__ __launch_bounds__(256) void setup_a(
    const int* __restrict__ dst, int* __restrict__ counts,
    const float* __restrict__ Wm1_h, const float* __restrict__ bm1_h,
    const float* __restrict__ Wm1_o, const float* __restrict__ bm1_o,
    const float* __restrict__ Wm2_h, const float* __restrict__ bm2_h,
    const float* __restrict__ Wm2_o, const float* __restrict__ bm2_o,
    const float* __restrict__ W2_h,  const float* __restrict__ b2_h,
    const float* __restrict__ W2_o,  const float* __restrict__ b2_o,
    const float* __restrict__ Wm1_d,
    bf16* __restrict__ Wm1B_h, bf16* __restrict__ Wm1B_o,
    bf16* __restrict__ Wm2B_h, bf16* __restrict__ Wm2B_o,
    bf16* __restrict__ W2B_h,  bf16* __restrict__ W2B_o,
    bf16* __restrict__ SelB,   float* __restrict__ Wm1T_d,
    const float* __restrict__ features, const float* __restrict__ W1_d,
    const float* __restrict__ b1_d, float* __restrict__ bufA) {
    int b = blockIdx.x, t = threadIdx.x;
    if (b < 3125) {                                  // count
        int e = b * 256 + t;
        if (e < N_EDGES) atomicAdd(&counts[dst[e]], 1);
    } else if (b < 3311) {                           // pack_all
        int pb = b - 3125;
        if (pb < 52)       dev_pack_wm1(pb * 256 + t, Wm1_h, bm1_h, Wm1B_h);
        else if (pb < 104) dev_pack_wm1((pb - 52) * 256 + t, Wm1_o, bm1_o, Wm1B_o);
        else if (pb < 132) dev_pack_wm2((pb - 104) * 256 + t, Wm2_h, bm2_h, Wm2B_h);
        else if (pb < 160) dev_pack_wm2((pb - 132) * 256 + t, Wm2_o, bm2_o, Wm2B_o);
        else if (pb < 164) dev_pack_w2h((pb - 160) * 256 + t, W2_h, b2_h, W2B_h);
        else if (pb < 166) dev_pack_w2o((pb - 164) * 256 + t, W2_o, b2_o, W2B_o);
        else if (pb < 182) dev_pack_sel((pb - 166) * 256 + t, SelB);
        else {
            int i = (pb - 182) * 256 + t;
            if (i < C_MSG * 4) Wm1T_d[i] = Wm1_d[(i & 3) * C_MSG + (i >> 2)];
        }
    } else {                                         // node term, layer d
        int n = (b - 3311) * 256 + t;
        if (n < N_NODES) {
            float xv = features[n];
            for (int o = 0; o < 30; ++o)
                bufA[n * 30 + o] = fmaf(xv, W1_d[o], b1_d[o]);
        }
    }
}

// Parallel scan over counts
__global__ __launch_bounds__(256) void scan_kernel(const int* __restrict__ counts,
                                                   int* __restrict__ offsets,
                                                   int* __restrict__ cursor) {
    __shared__ int ws[4];
    const int b = blockIdx.x, t = threadIdx.x;
    const int lane = t & 63, wv = t >> 6;
    int acc = 0;
    for (int i = t; i < b * 256; i += 256) acc += counts[i];
#pragma unroll
    for (int d = 32; d > 0; d >>= 1) acc += __shfl_xor(acc, d);
    if (lane == 0) ws[wv] = acc;
    __syncthreads();
    int base = ws[0] + ws[1] + ws[2] + ws[3];
    __syncthreads();
    int i = b * 256 + t;
    int v = (i < N_NODES) ? counts[i] : 0;
    int inc = v;
#pragma unroll
    for (int d = 1; d < 64; d <<= 1) {
        int u = __shfl_up(inc, d);
        if (lane >= d) inc += u;
    }
    if (lane == 63) ws[wv] = inc;
    __syncthreads();
    int waveoff = 0;
    for (int k = 0; k < wv; ++k) waveoff += ws[k];
    int excl = base + waveoff + inc - v;
    if (i < N_NODES) { offsets[i] = excl; cursor[i] = excl; }
    if (i == N_NODES - 1) offsets[N_NODES] = excl + v;
}

// scatter: int4 stream {src, dst, ewbf, perm} in perm order + fp32 ew pair
// (ewp) in perm order so edge_d reads ew COALESCED.
__global__ __launch_bounds__(256) void scatter_kernel(
    const int* __restrict__ src, const int* __restrict__ dst,
    const float* __restrict__ ew, int* __restrict__ cursor,
    int4* __restrict__ edata, float2* __restrict__ ewp) {
    int e = blockIdx.x * 256 + threadIdx.x;
    if (e < N_EDGES) {
        int d = dst[e];
        float e0 = ew[2 * e], e1 = ew[2 * e + 1];
        int p = atomicAdd(&cursor[d], 1);
        edata[p] = make_int4(src[e], d, (int)pk_bf16(e0, e1), e);
        ewp[p] = make_float2(e0, e1);
    }
}

// ===========================================================================
// Layer-d edge kernel (CIN=1): full-fp32 VALU path, perm order.
// Wm1T/bm1/Wm2/bm2 staged in 4.8KB LDS (same values, same fma order ->
// bit-identical) + unroll 4 for MLP on the serial j chain.
// ===========================================================================
__global__ __launch_bounds__(256) void edge_d_kernel(
    const float* __restrict__ x, const int4* __restrict__ edata,
    const float2* __restrict__ ewp,
    const float* __restrict__ Wm1T, const float* __restrict__ bm1,
    const float* __restrict__ Wm2, const float* __restrict__ bm2,
    const float* __restrict__ W2, const float* __restrict__ b2, bf16* __restrict__ msg)
{
    __shared__ float sw[C_MSG * 6 + 1];  // [0,800) Wm1T, [800,1000) bm1,
                                         // [1000,1200) Wm2, [1200] bm2
    for (int i = threadIdx.x; i < C_MSG * 6 + 1; i += 256) {
        float v;
        if (i < C_MSG * 4)            v = Wm1T[i];
        else if (i < C_MSG * 5)       v = bm1[i - C_MSG * 4];
        else if (i < C_MSG * 6)       v = Wm2[i - C_MSG * 5];
        else                          v = bm2[0];
        sw[i] = v;
    }
    __syncthreads();

    int t = blockIdx.x * 256 + threadIdx.x;
    int4 ed = edata[t];
    float xi = x[ed.y], xj = x[ed.x];
    float2 e01 = ewp[t];
    float e0 = e01.x, e1 = e01.y;
    float m = sw[C_MSG * 6];
#pragma unroll 4
    for (int j = 0; j < C_MSG; ++j) {
        const float* wr = sw + j * 4;
        float h = sw[C_MSG * 4 + j];
        h = fmaf(xi, wr[0], h);
        h = fmaf(xj, wr[1], h);
        h = fmaf(e0, wr[2], h);
        h = fmaf(e1, wr[3], h);
        h = fmaxf(h, 0.f);
        m = fmaf(h, sw[C_MSG * 5 + j], m);
    }
    float md = m * (xi - xj);
    for (int o = 0; o < 15; ++o) {
        float f0 = fmaf(md, W2[2 * o], b2[2 * o]);
        float f1 = fmaf(md, W2[2 * o + 1], b2[2 * o + 1]);
        *(unsigned int*)(msg + (size_t)t * 32 + 2 * o) = pk_bf16(f0, f1);
    }
}

// ===========================================================================
// MFMA edge kernel v20: v17 structure (T=4, bit-exact) with Wm2 moved OUT of
// LDS to cross the 4-blocks/CU occupancy threshold.
//  R11 floor arithmetic: per tile ~7 LDS RAW round-trips + 50 dependent
//  MFMAs ≈ 2500 cyc serial chain; wave = 4 tiles ≈ 10K cyc; 48.8 wave-
//  groups/SIMD / 3 concurrent ≈ 163K cyc ≈ 68us — matches measured 63-67.
//  Kernel is LATENCY-CHAIN-bound, divided by waves/SIMD; 3 was forced by
//  LDS 53248B (weights 40960 + chunks 12288) -> 3 blocks/CU.
//  v20: stage ONLY Wm1 (26624B) + chunks (12288B) = 38912B <= 40960
//  -> 4 blocks/CU = 16 waves/CU (+33% concurrency). Wm2B reads revert to
//  global: 14/tile, wave-uniform, from a 14KB L1-resident buffer (cheap;
//  v13's win was removing gather-competing loads, these are broadcast hits).
//  launch_bounds(256,4): VGPR cap 128 (current 68, safe).
//  Same values, same MFMA order -> bit-identical (absmax 1.41671e+22).
//  R11 levers (setprio, XCD swizzle) removed: both measured neutral.
//  DO NOT re-attempt pair-outer chunk reuse (v15/v16 failed correctness).
//  Spill tripwire: WRITE_SIZE ~50MB.
// ===========================================================================

#define LOAD_FRAGS(P, ED) do {                                                \
    const bf16* rd_ = xc + (size_t)(ED).y * 64 + quad * 8;                    \
    const bf16* rs_ = xc + (size_t)(ED).x * 64 + quad * 8;                    \
    P##A0 = *(const bf16x8*)(rd_);                                            \
    P##a2 = *(const bf16x8*)(rd_ + 32);                                       \
    P##A1 = *(const bf16x8*)(rs_);                                            \
    P##a3 = *(const bf16x8*)(rs_ + 32);                                       \
} while (0)

// Per-tile compute, v13 op order. Uses in-scope: Wm1L, Wm2B, cA, cB, cP,
// col, quad, row0, lane, SelB, W2B, msg, COUT.
#define COMPUTE_TILE(P, EDZ, EBASE) do {                                      \
    if (quad == 3) {                                                          \
        union { unsigned int u; bf16 b[2]; } cv_;                             \
        cv_.u = (unsigned int)(EDZ);                                          \
        P##A1[6] = cv_.b[0];                                                  \
        P##A1[7] = cv_.b[1];                                                  \
    }                                                                         \
    /* fused GEMM1/GEMM2: pair p_ -> chunk -> kt=p_ accumulation */           \
    f32x4 m0_ = {0.f,0.f,0.f,0.f}, m1_ = {0.f,0.f,0.f,0.f};                   \
    _Pragma("unroll")                                                         \
    for (int p_ = 0; p_ < 6; ++p_) {                                          \
        char* cb_ = (p_ & 1) ? cB : cA;                                       \
        const bf16* Wf_ = Wm1L + (4 * p_) * 512 + lane * 8;                   \
        bf16x8 be0_ = *(const bf16x8*)(Wf_);                                  \
        bf16x8 be1_ = *(const bf16x8*)(Wf_ + 512);                            \
        bf16x8 bo0_ = *(const bf16x8*)(Wf_ + 1024);                           \
        bf16x8 bo1_ = *(const bf16x8*)(Wf_ + 1536);                           \
        f32x4 ae_ = {0.f,0.f,0.f,0.f}, ao_ = {0.f,0.f,0.f,0.f};               \
        ae_ = MF(P##A0, be0_, ae_);                                           \
        ae_ = MF(P##A1, be1_, ae_);                                           \
        ao_ = MF(P##A0, bo0_, ao_);                                           \
        ao_ = MF(P##A1, bo1_, ao_);                                           \
        _Pragma("unroll")                                                     \
        for (int rg_ = 0; rg_ < 4; ++rg_) {                                   \
            int row_ = row0 + rg_, wb_ = 4 * col;                             \
            unsigned int u_ = pk_bf16(fmaxf(ae_[rg_],0.f), fmaxf(ao_[rg_],0.f)); \
            *(unsigned int*)(cb_ + row_ * 64 + ((wb_ & 48) ^ ((row_ & 3) << 4)) \
                             + (wb_ & 15)) = u_;                              \
        }                                                                     \
        bf16x8 a_ = *(const bf16x8*)(cb_ + col * 64 +                         \
                                     ((quad << 4) ^ ((col & 3) << 4)));       \
        m0_ = MF(a_, *(const bf16x8*)(Wm2B + (size_t)p_ * 512 + lane * 8), m0_); \
        m1_ = MF(a_, *(const bf16x8*)(Wm2B + (size_t)(7 + p_) * 512 + lane * 8), m1_); \
    }                                                                         \
    {   /* leftover N-tile 12 (kt=6): cols 192..199 real, pad const in cP */  \
        const bf16* Wf_ = Wm1L + 24 * 512 + lane * 8;                         \
        bf16x8 b0_ = *(const bf16x8*)(Wf_);                                   \
        bf16x8 b1_ = *(const bf16x8*)(Wf_ + 512);                             \
        f32x4 acc_ = {0.f,0.f,0.f,0.f};                                       \
        acc_ = MF(P##A0, b0_, acc_);                                          \
        acc_ = MF(P##A1, b1_, acc_);                                          \
        if (col < 8) {                                                        \
            _Pragma("unroll")                                                 \
            for (int rg_ = 0; rg_ < 4; ++rg_) {                               \
                int row_ = row0 + rg_;                                        \
                *(bf16*)(cP + row_ * 64 + ((row_ & 3) << 4) + 2 * col) =      \
                    (bf16)fmaxf(acc_[rg_], 0.f);                              \
            }                                                                 \
        }                                                                     \
        bf16x8 a_ = *(const bf16x8*)(cP + col * 64 +                          \
                                     ((quad << 4) ^ ((col & 3) << 4)));       \
        m0_ = MF(a_, *(const bf16x8*)(Wm2B + (size_t)6 * 512 + lane * 8), m0_); \
        m1_ = MF(a_, *(const bf16x8*)(Wm2B + (size_t)13 * 512 + lane * 8), m1_); \
    }                                                                         \
    /* selector GEMM: diff[16x32] (rows 30/31 zero -> ew patch inert) */      \
    f32x4 dc0_ = {0.f,0.f,0.f,0.f}, dc1_ = {0.f,0.f,0.f,0.f};                 \
    dc0_ = MF(P##A0, *(const bf16x8*)(SelB + (size_t)0*512 + lane*8), dc0_);  \
    dc1_ = MF(P##A0, *(const bf16x8*)(SelB + (size_t)1*512 + lane*8), dc1_);  \
    dc0_ = MF(P##A1, *(const bf16x8*)(SelB + (size_t)2*512 + lane*8), dc0_);  \
    dc1_ = MF(P##A1, *(const bf16x8*)(SelB + (size_t)3*512 + lane*8), dc1_);  \
    dc0_ = MF(P##a2, *(const bf16x8*)(SelB + (size_t)4*512 + lane*8), dc0_);  \
    dc1_ = MF(P##a2, *(const bf16x8*)(SelB + (size_t)5*512 + lane*8), dc1_);  \
    dc0_ = MF(P##a3, *(const bf16x8*)(SelB + (size_t)6*512 + lane*8), dc0_);  \
    dc1_ = MF(P##a3, *(const bf16x8*)(SelB + (size_t)7*512 + lane*8), dc1_);  \
    /* md = m*diff -> chunkA -> GEMM3 A-frag */                               \
    _Pragma("unroll")                                                         \
    for (int rg_ = 0; rg_ < 4; ++rg_) {                                       \
        int row_ = row0 + rg_, wb_ = 4 * col;                                 \
        unsigned int u_ = (col == 15) ? pk_bf16(1.f, 0.f)                     \
                        : pk_bf16(m0_[rg_]*dc0_[rg_], m1_[rg_]*dc1_[rg_]);    \
        *(unsigned int*)(cA + row_ * 64 + ((wb_ & 48) ^ ((row_ & 3) << 4))    \
                         + (wb_ & 15)) = u_;                                  \
    }                                                                         \
    bf16x8 am_ = *(const bf16x8*)(cA + col * 64 +                             \
                                  ((quad << 4) ^ ((col & 3) << 4)));          \
    /* GEMM3: md[16x32] @ W2[32xN] -> msg */                                  \
    if (COUT == 30) {                                                         \
        f32x4 c0_ = {0.f,0.f,0.f,0.f}, c1_ = {0.f,0.f,0.f,0.f};               \
        c0_ = MF(am_, *(const bf16x8*)(W2B + lane*8), c0_);                   \
        c1_ = MF(am_, *(const bf16x8*)(W2B + 512 + lane*8), c1_);             \
        _Pragma("unroll")                                                     \
        for (int rg_ = 0; rg_ < 4; ++rg_)                                     \
            *(unsigned int*)(msg + (size_t)((EBASE) + row0 + rg_)*32 + 2*col) = \
                pk_bf16(c0_[rg_], c1_[rg_]);                                  \
    } else {                                                                  \
        /* COUT=1: compact msg1[e] — one 8B store per col==0 lane */          \
        f32x4 c0_ = {0.f,0.f,0.f,0.f};                                        \
        c0_ = MF(am_, *(const bf16x8*)(W2B + lane*8), c0_);                   \
        if (col == 0) {                                                       \
            union { bf16 h[4]; unsigned long long u; } pk4_;                  \
            _Pragma("unroll")                                                 \
            for (int rg_ = 0; rg_ < 4; ++rg_) pk4_.h[rg_] = (bf16)c0_[rg_];   \
            *(unsigned long long*)(msg + ((EBASE) + row0)) = pk4_.u;          \
        }                                                                     \
    }                                                                         \
} while (0)

template<int COUT>
__global__ __launch_bounds__(256, 4) void edge_mfma(
    const bf16* __restrict__ xc, const int4* __restrict__ edata,
    const bf16* __restrict__ Wm1B, const bf16* __restrict__ SelB,
    const bf16* __restrict__ Wm2B, const bf16* __restrict__ W2B,
    bf16* __restrict__ msg)
{
    // [0,13312): Wm1 26 frags; [13312,19456): 4 waves x 3 x 512 chunk
    // buffers.  38912 B total -> 4 blocks/CU.
    __shared__ __align__(16) bf16 smem[19456];
    bf16* Wm1L = smem;

    const int tid = threadIdx.x, w = tid >> 6, lane = tid & 63;
    const int col = lane & 15, quad = lane >> 4, row0 = quad * 4;
    const int myrow = w * 16;
    const int blk = blockIdx.x * 256;             // 4 tiles x 64 edges

    // ---- issue all 4 edata loads FIRST (fly during staging) ----
    const int eoff = myrow + col;
    int4 ed0 = edata[blk + 0 * 64 + eoff];
    int4 ed1 = edata[blk + 1 * 64 + eoff];
    int4 ed2 = edata[blk + 2 * 64 + eoff];
    int4 ed3 = edata[blk + 3 * 64 + eoff];

    // ---- stage Wm1 only: 1664 x 16B chunks, 7 per thread ----
#pragma unroll
    for (int i = 0; i < 7; ++i) {
        int idx = tid + i * 256;
        if (idx < 1664)
            *((bf16x8*)smem + idx) = *((const bf16x8*)Wm1B + idx);
    }
    __syncthreads();

    char* cbase = (char*)(smem + 13312 + w * 1536);
    char* cA = cbase;
    char* cB = cbase + 1024;
    char* cP = cbase + 2048;

    // cP pad slots 1..3 (global cols 200..223): slot1 elem0 = bm2 bias row
    // marker (1.0), rest 0. Written once; tiles only rewrite slot 0.
    if (lane < 48) {
        int r = lane / 3, s = 1 + (lane - r * 3);
        bf16x8 z = {};
        if (s == 1) z[0] = (bf16)1.f;
        *(bf16x8*)(cP + r * 64 + ((s << 4) ^ ((r & 3) << 4))) = z;
    }

    // ---- rolling 2-deep pipeline over 4 tiles ----
    bf16x8 pA0, pA1, pa2, pa3, qA0, qA1, qa2, qa3;
    LOAD_FRAGS(p, ed0);
    LOAD_FRAGS(q, ed1);

    COMPUTE_TILE(p, ed0.z, blk + 0 * 64 + myrow);
    LOAD_FRAGS(p, ed2);
    COMPUTE_TILE(q, ed1.z, blk + 1 * 64 + myrow);
    LOAD_FRAGS(q, ed3);
    COMPUTE_TILE(p, ed2.z, blk + 2 * 64 + myrow);
    COMPUTE_TILE(q, ed3.z, blk + 3 * 64 + myrow);
}

// ===========================================================================
// Fused aggregation + next node term. 16 lanes per node; width-16 shuffles;
// fma order identical to the original node_kernel -> numerically identical.
// j-loop unrolled 8 (adds still folded in ascending-j order -> bit-identical).
// ===========================================================================
template<int CNEXT>
__global__ __launch_bounds__(256) void agg_fused(
    const bf16* __restrict__ msg, const int* __restrict__ offsets,
    const float* __restrict__ bufc,
    const float* __restrict__ W1n, const float* __restrict__ b1n,
    float* __restrict__ bufn,
    bf16* __restrict__ xc) {
    int gh = (blockIdx.x * 256 + threadIdx.x) >> 4;
    int lane = threadIdx.x & 15;
    int s0 = offsets[gh], s1 = offsets[gh + 1];
    float r0 = 0.f, r1 = 0.f;
    if (lane < 15) {
        float v0 = 0.f, v1 = 0.f;
        const unsigned int* mp =
            (const unsigned int*)(msg + (size_t)s0 * 32 + lane * 2);
        int cnt = s1 - s0, j = 0;
        for (; j + 8 <= cnt; j += 8) {
            unsigned int u0 = mp[(size_t)(j + 0) * 16];
            unsigned int u1 = mp[(size_t)(j + 1) * 16];
            unsigned int u2 = mp[(size_t)(j + 2) * 16];
            unsigned int u3 = mp[(size_t)(j + 3) * 16];
            unsigned int u4 = mp[(size_t)(j + 4) * 16];
            unsigned int u5 = mp[(size_t)(j + 5) * 16];
            unsigned int u6 = mp[(size_t)(j + 6) * 16];
            unsigned int u7 = mp[(size_t)(j + 7) * 16];
            union { unsigned int u; bf16 b[2]; } c0, c1, c2, c3, c4, c5, c6, c7;
            c0.u = u0; c1.u = u1; c2.u = u2; c3.u = u3;
            c4.u = u4; c5.u = u5; c6.u = u6; c7.u = u7;
            v0 += (float)c0.b[0]; v1 += (float)c0.b[1];
            v0 += (float)c1.b[0]; v1 += (float)c1.b[1];
            v0 += (float)c2.b[0]; v1 += (float)c2.b[1];
            v0 += (float)c3.b[0]; v1 += (float)c3.b[1];
            v0 += (float)c4.b[0]; v1 += (float)c4.b[1];
            v0 += (float)c5.b[0]; v1 += (float)c5.b[1];
            v0 += (float)c6.b[0]; v1 += (float)c6.b[1];
            v0 += (float)c7.b[0]; v1 += (float)c7.b[1];
        }
        for (; j + 4 <= cnt; j += 4) {
            unsigned int u0 = mp[(size_t)(j + 0) * 16];
            unsigned int u1 = mp[(size_t)(j + 1) * 16];
            unsigned int u2 = mp[(size_t)(j + 2) * 16];
            unsigned int u3 = mp[(size_t)(j + 3) * 16];
            union { unsigned int u; bf16 b[2]; } c0, c1, c2, c3;
            c0.u = u0; c1.u = u1; c2.u = u2; c3.u = u3;
            v0 += (float)c0.b[0]; v1 += (float)c0.b[1];
            v0 += (float)c1.b[0]; v1 += (float)c1.b[1];
            v0 += (float)c2.b[0]; v1 += (float)c2.b[1];
            v0 += (float)c3.b[0]; v1 += (float)c3.b[1];
        }
        for (; j < cnt; ++j) {
            union { unsigned int u; bf16 b[2]; } cv;
            cv.u = mp[(size_t)j * 16];
            v0 += (float)cv.b[0]; v1 += (float)cv.b[1];
        }
        float f0 = bufc[(size_t)gh * 30 + 2 * lane] + v0;
        float f1 = bufc[(size_t)gh * 30 + 2 * lane + 1] + v1;
        r0 = fmaxf(f0, 0.f);
        r1 = fmaxf(f1, 0.f);
        bf16 h0 = (bf16)r0, h1 = (bf16)r1;
        union { bf16 h[2]; unsigned int u; } hi;
        hi.h[0] = h0; hi.h[1] = h1;
        *(unsigned int*)(xc + (size_t)gh * 64 + 2 * lane) = hi.u;
        *(unsigned int*)(xc + (size_t)gh * 64 + 32 + 2 * lane) =
            pk_bf16(r0 - (float)h0, r1 - (float)h1);
    } else {
        *(unsigned int*)(xc + (size_t)gh * 64 + 30) = pk_bf16(1.f, 0.f);
        *(unsigned int*)(xc + (size_t)gh * 64 + 62) = 0u;
    }
    // ---- next node term (fma order == original node_kernel) ----
    if (CNEXT == 30) {
        float acc0 = 0.f, acc1 = 0.f;
        if (lane < 15) { acc0 = b1n[2 * lane]; acc1 = b1n[2 * lane + 1]; }
        for (int k2 = 0; k2 < 15; ++k2) {
            float rk0 = __shfl(r0, k2, 16);
            float rk1 = __shfl(r1, k2, 16);
            if (lane < 15) {
                const float* w0 = W1n + (2 * k2) * 30 + 2 * lane;
                const float* w1 = W1n + (2 * k2 + 1) * 30 + 2 * lane;
                acc0 = fmaf(rk0, w0[0], acc0);
                acc1 = fmaf(rk0, w0[1], acc1);
                acc0 = fmaf(rk1, w1[0], acc0);
                acc1 = fmaf(rk1, w1[1], acc1);
            }
        }
        if (lane < 15) {
            bufn[(size_t)gh * 30 + 2 * lane] = acc0;
            bufn[(size_t)gh * 30 + 2 * lane + 1] = acc1;
        }
    } else {
        float acc = b1n[0];
        for (int k2 = 0; k2 < 15; ++k2) {
            float rk0 = __shfl(r0, k2, 16);
            float rk1 = __shfl(r1, k2, 16);
            acc = fmaf(rk0, W1n[2 * k2], acc);
            acc = fmaf(rk1, W1n[2 * k2 + 1], acc);
        }
        if (lane == 0) bufn[gh] = acc;
    }
}

// Final aggregation, compact msg1[e]: out[gh] += sum (same lane->j order)
__global__ __launch_bounds__(256) void agg_last(const bf16* __restrict__ msg1,
                                                const int* __restrict__ offsets,
                                                float* __restrict__ out) {
    int gh = (blockIdx.x * 256 + threadIdx.x) >> 5;
    int lane = threadIdx.x & 31;
    int s0 = offsets[gh], s1 = offsets[gh + 1];
    float v = 0.f;
    for (int j = s0 + lane; j < s1; j += 32) v += (float)msg1[j];
#pragma unroll
    for (int o = 16; o > 0; o >>= 1) v += __shfl_xor(v, o);
    if (lane == 0) out[gh] += v;
}

// ===========================================================================
extern "C" void kernel_launch(void* const* d_in, const int* in_sizes, int n_in,
                              void* d_out, int out_size, void* d_ws, size_t ws_size,
                              hipStream_t stream) {
    const float* features = (const float*)d_in[0];
    const int*   edges    = (const int*)d_in[1];
    const float* ew       = (const float*)d_in[2];

    const float* W1_d  = (const float*)d_in[3];
    const float* b1_d  = (const float*)d_in[4];
    const float* Wm1_d = (const float*)d_in[5];
    const float* bm1_d = (const float*)d_in[6];
    const float* Wm2_d = (const float*)d_in[7];
    const float* bm2_d = (const float*)d_in[8];
    const float* W2_d  = (const float*)d_in[9];
    const float* b2_d  = (const float*)d_in[10];

    const float* W1_h  = (const float*)d_in[11];
    const float* b1_h  = (const float*)d_in[12];
    const float* Wm1_h = (const float*)d_in[13];
    const float* bm1_h = (const float*)d_in[14];
    const float* Wm2_h = (const float*)d_in[15];
    const float* bm2_h = (const float*)d_in[16];
    const float* W2_h  = (const float*)d_in[17];
    const float* b2_h  = (const float*)d_in[18];

    const float* W1_o  = (const float*)d_in[19];
    const float* b1_o  = (const float*)d_in[20];
    const float* Wm1_o = (const float*)d_in[21];
    const float* bm1_o = (const float*)d_in[22];
    const float* Wm2_o = (const float*)d_in[23];
    const float* bm2_o = (const float*)d_in[24];
    const float* W2_o  = (const float*)d_in[25];
    const float* b2_o  = (const float*)d_in[26];

    const int* src = edges;
    const int* dst = edges + N_EDGES;
    float* out = (float*)d_out;

    // ---- workspace carve-up ----
    char* p = (char*)d_ws;
    auto alloc = [&](size_t bytes) { char* r = p; p += (bytes + 63) & ~(size_t)63; return r; };
    float* bufA    = (float*)alloc((size_t)N_NODES * 30 * 4);
    float* bufB    = (float*)alloc((size_t)N_NODES * 30 * 4);
    bf16*  msg     = (bf16*) alloc((size_t)N_EDGES * 32 * 2);
    bf16*  xc      = (bf16*) alloc((size_t)N_NODES * 64 * 2);
    int*   counts  = (int*)  alloc((size_t)N_NODES * 4);
    int*   offsets = (int*)  alloc((size_t)(N_NODES + 1) * 4);
    int*   cursor  = (int*)  alloc((size_t)N_NODES * 4);
    int4*  edata   = (int4*) alloc((size_t)N_EDGES * 16);
    float2* ewp    = (float2*)alloc((size_t)N_EDGES * 8);
    float* Wm1T_d  = (float*)alloc((size_t)C_MSG * 4 * 4);
    bf16*  Wm1B_h  = (bf16*) alloc((size_t)26 * 512 * 2);
    bf16*  Wm1B_o  = (bf16*) alloc((size_t)26 * 512 * 2);
    bf16*  Wm2B_h  = (bf16*) alloc((size_t)14 * 512 * 2);
    bf16*  Wm2B_o  = (bf16*) alloc((size_t)14 * 512 * 2);
    bf16*  W2B_h   = (bf16*) alloc((size_t)2 * 512 * 2);
    bf16*  W2B_o   = (bf16*) alloc((size_t)1 * 512 * 2);
    bf16*  SelB    = (bf16*) alloc((size_t)8 * 512 * 2);

    // ---- setup ----
    hipMemsetAsync(counts, 0, (size_t)N_NODES * 4, stream);
    setup_a<<<3507, 256, 0, stream>>>(dst, counts,
        Wm1_h, bm1_h, Wm1_o, bm1_o, Wm2_h, bm2_h, Wm2_o, bm2_o,
        W2_h, b2_h, W2_o, b2_o, Wm1_d,
        Wm1B_h, Wm1B_o, Wm2B_h, Wm2B_o, W2B_h, W2B_o, SelB, Wm1T_d,
        features, W1_d, b1_d, bufA);
    scan_kernel<<<(N_NODES + 255) / 256, 256, 0, stream>>>(counts, offsets, cursor);
    scatter_kernel<<<N_EDGES / 256, 256, 0, stream>>>(src, dst, ew, cursor, edata, ewp);

    dim3 tb(256);
    dim3 eb_mfma(N_EDGES / 256);   // 4 tiles of 64 edges per block
    dim3 eb_valu(N_EDGES / 256);
    dim3 ab16(N_NODES * 16 / 256);
    dim3 ab32(N_NODES * 32 / 256);

    // ---- layer d ----
    edge_d_kernel<<<eb_valu, tb, 0, stream>>>(features, edata, ewp,
        Wm1T_d, bm1_d, Wm2_d, bm2_d, W2_d, b2_d, msg);
    agg_fused<30><<<ab16, tb, 0, stream>>>(msg, offsets, bufA, W1_h, b1_h, bufB, xc);

    // ---- h1 ----
    edge_mfma<30><<<eb_mfma, tb, 0, stream>>>(xc, edata,
        Wm1B_h, SelB, Wm2B_h, W2B_h, msg);
    agg_fused<30><<<ab16, tb, 0, stream>>>(msg, offsets, bufB, W1_h, b1_h, bufA, xc);

    // ---- h2 ----
    edge_mfma<30><<<eb_mfma, tb, 0, stream>>>(xc, edata,
        Wm1B_h, SelB, Wm2B_h, W2B_h, msg);
    agg_fused<30><<<ab16, tb, 0, stream>>>(msg, offsets, bufA, W1_h, b1_h, bufB, xc);

    // ---- h3 (next node term = output layer -> writes d_out) ----
    edge_mfma<30><<<eb_mfma, tb, 0, stream>>>(xc, edata,
        Wm1B_h, SelB, Wm2B_h, W2B_h, msg);
    agg_fused<1><<<ab16, tb, 0, stream>>>(msg, offsets, bufB, W1_o, b1_o, out, xc);

    // ---- output layer (compact msg1) ----
    edge_mfma<1><<<eb_mfma, tb, 0, stream>>>(xc, edata,
        Wm1B_o, SelB, Wm2B_o, W2B_o, msg);
    agg_last<<<ab32, tb, 0, stream>>>(msg, offsets, out);
}

// Round 13
// 573.778 us; speedup vs baseline: 1.1908x; 1.1908x over previous
//
#include <hip/hip_runtime.h>

#define N_NODES 50000
#define N_EDGES 800000
#define C_MSG 200

typedef __bf16 bf16;
typedef __attribute__((ext_vector_type(8))) __bf16 bf16x8;
typedef __attribute__((ext_vector_type(4))) float f32x4;

static __device__ __forceinline__ unsigned int pk_bf16(float a, float b) {
    union { bf16 h[2]; unsigned int u; } cv;
    cv.h[0] = (bf16)a; cv.h[1] = (bf16)b;
    return cv.u;
}

static __device__ __forceinline__ f32x4 MF(bf16x8 a, bf16x8 b, f32x4 c) {
    return __builtin_amdgcn_mfma_f32_16x16x32_bf16(a, b, c, 0, 0, 0);
}

// ===========================================================================
// Weight packers (device fns) -> MFMA B-frag order (16x16x32), biases folded.
// Fragment f at out[f*512 + lane*8 + i]; lane holds B[k][n], k=kt*32+(lane>>4)*8+i.
// Paired N-tiles: pair p covers cols p*32 + 2*(lane&15) + parity.
// ===========================================================================
static __device__ void dev_pack_wm1(int tid, const float* W, const float* bm1,
                                    bf16* out) {
    int i = tid & 7, lane = (tid >> 3) & 63, rest = tid >> 9;
    int kt = rest % 2, t = rest / 2;
    int k = kt * 32 + ((lane >> 4) * 8) + i;
    int c = lane & 15;
    int n = (t < 12) ? ((t >> 1) * 32 + 2 * c + (t & 1)) : (192 + c);
    float v = 0.f;
    if (n < C_MSG) {
        if (k < 30)       v = W[k * C_MSG + n];
        else if (k == 30) v = bm1[n];
        else if (k >= 32) v = W[(k - 2) * C_MSG + n];
    }
    out[tid] = (bf16)v;
}

static __device__ void dev_pack_wm2(int tid, const float* W, const float* bm2,
                                    bf16* out) {
    int i = tid & 7, lane = (tid >> 3) & 63, rest = tid >> 9;
    int kt = rest % 7, nt = rest / 7;
    int k = kt * 32 + ((lane >> 4) * 8) + i;
    int n = 2 * (lane & 15) + nt;
    float v = 0.f;
    if (n < 30) {
        if (k < C_MSG)       v = W[k * 30 + n];
        else if (k == C_MSG) v = bm2[n];
    }
    out[tid] = (bf16)v;
}

static __device__ void dev_pack_w2h(int tid, const float* W, const float* b2,
                                    bf16* out) {
    int i = tid & 7, lane = (tid >> 3) & 63, nt = tid >> 9;
    int k = ((lane >> 4) * 8) + i;
    int n = 2 * (lane & 15) + nt;
    float v = 0.f;
    if (n < 30) {
        if (k < 30)       v = W[k * 30 + n];
        else if (k == 30) v = b2[n];
    }
    out[tid] = (bf16)v;
}

static __device__ void dev_pack_w2o(int tid, const float* W, const float* b2,
                                    bf16* out) {
    int i = tid & 7, lane = (tid >> 3) & 63;
    int k = ((lane >> 4) * 8) + i;
    int n = lane & 15;
    float v = 0.f;
    if (n == 0) {
        if (k < 30)       v = W[k];
        else if (k == 30) v = b2[0];
    }
    out[tid] = (bf16)v;
}

static __device__ void dev_pack_sel(int tid, bf16* out) {
    int i = tid & 7, lane = (tid >> 3) & 63, f = tid >> 9;
    int kt = f >> 1, nt = f & 1;
    int kloc = ((lane >> 4) * 8) + i;
    int n = 2 * (lane & 15) + nt;
    float v = (kloc == n && n < 30) ? ((kt & 1) ? -1.f : 1.f) : 0.f;
    out[tid] = (bf16)v;
}

// ===========================================================================
// setup_a: count (3125 blocks) + pack_all (186) + node_d (196) in ONE dispatch
// ===========================================================================
__global__ __launch_bounds__(256) void setup_a(
    const int* __restrict__ dst, int* __restrict__ counts,
    const float* __restrict__ Wm1_h, const float* __restrict__ bm1_h,
    const float* __restrict__ Wm1_o, const float* __restrict__ bm1_o,
    const float* __restrict__ Wm2_h, const float* __restrict__ bm2_h,
    const float* __restrict__ Wm2_o, const float* __restrict__ bm2_o,
    const float* __restrict__ W2_h,  const float* __restrict__ b2_h,
    const float* __restrict__ W2_o,  const float* __restrict__ b2_o,
    const float* __restrict__ Wm1_d,
    bf16* __restrict__ Wm1B_h, bf16* __restrict__ Wm1B_o,
    bf16* __restrict__ Wm2B_h, bf16* __restrict__ Wm2B_o,
    bf16* __restrict__ W2B_h,  bf16* __restrict__ W2B_o,
    bf16* __restrict__ SelB,   float* __restrict__ Wm1T_d,
    const float* __restrict__ features, const float* __restrict__ W1_d,
    const float* __restrict__ b1_d, float* __restrict__ bufA) {
    int b = blockIdx.x, t = threadIdx.x;
    if (b < 3125) {                                  // count
        int e = b * 256 + t;
        if (e < N_EDGES) atomicAdd(&counts[dst[e]], 1);
    } else if (b < 3311) {                           // pack_all
        int pb = b - 3125;
        if (pb < 52)       dev_pack_wm1(pb * 256 + t, Wm1_h, bm1_h, Wm1B_h);
        else if (pb < 104) dev_pack_wm1((pb - 52) * 256 + t, Wm1_o, bm1_o, Wm1B_o);
        else if (pb < 132) dev_pack_wm2((pb - 104) * 256 + t, Wm2_h, bm2_h, Wm2B_h);
        else if (pb < 160) dev_pack_wm2((pb - 132) * 256 + t, Wm2_o, bm2_o, Wm2B_o);
        else if (pb < 164) dev_pack_w2h((pb - 160) * 256 + t, W2_h, b2_h, W2B_h);
        else if (pb < 166) dev_pack_w2o((pb - 164) * 256 + t, W2_o, b2_o, W2B_o);
        else if (pb < 182) dev_pack_sel((pb - 166) * 256 + t, SelB);
        else {
            int i = (pb - 182) * 256 + t;
            if (i < C_MSG * 4) Wm1T_d[i] = Wm1_d[(i & 3) * C_MSG + (i >> 2)];
        }
    } else {                                         // node term, layer d
        int n = (b - 3311) * 256 + t;
        if (n < N_NODES) {
            float xv = features[n];
            for (int o = 0; o < 30; ++o)
                bufA[n * 30 + o] = fmaf(xv, W1_d[o], b1_d[o]);
        }
    }
}

// Parallel scan over counts
__global__ __launch_bounds__(256) void scan_kernel(const int* __restrict__ counts,
                                                   int* __restrict__ offsets,
                                                   int* __restrict__ cursor) {
    __shared__ int ws[4];
    const int b = blockIdx.x, t = threadIdx.x;
    const int lane = t & 63, wv = t >> 6;
    int acc = 0;
    for (int i = t; i < b * 256; i += 256) acc += counts[i];
#pragma unroll
    for (int d = 32; d > 0; d >>= 1) acc += __shfl_xor(acc, d);
    if (lane == 0) ws[wv] = acc;
    __syncthreads();
    int base = ws[0] + ws[1] + ws[2] + ws[3];
    __syncthreads();
    int i = b * 256 + t;
    int v = (i < N_NODES) ? counts[i] : 0;
    int inc = v;
#pragma unroll
    for (int d = 1; d < 64; d <<= 1) {
        int u = __shfl_up(inc, d);
        if (lane >= d) inc += u;
    }
    if (lane == 63) ws[wv] = inc;
    __syncthreads();
    int waveoff = 0;
    for (int k = 0; k < wv; ++k) waveoff += ws[k];
    int excl = base + waveoff + inc - v;
    if (i < N_NODES) { offsets[i] = excl; cursor[i] = excl; }
    if (i == N_NODES - 1) offsets[N_NODES] = excl + v;
}

// scatter: int4 stream {src, dst, ewbf, perm} in perm order + fp32 ew pair
// (ewp) in perm order so edge_d reads ew COALESCED.
__global__ __launch_bounds__(256) void scatter_kernel(
    const int* __restrict__ src, const int* __restrict__ dst,
    const float* __restrict__ ew, int* __restrict__ cursor,
    int4* __restrict__ edata, float2* __restrict__ ewp) {
    int e = blockIdx.x * 256 + threadIdx.x;
    if (e < N_EDGES) {
        int d = dst[e];
        float e0 = ew[2 * e], e1 = ew[2 * e + 1];
        int p = atomicAdd(&cursor[d], 1);
        edata[p] = make_int4(src[e], d, (int)pk_bf16(e0, e1), e);
        ewp[p] = make_float2(e0, e1);
    }
}

// ===========================================================================
// Layer-d edge kernel (CIN=1): full-fp32 VALU path, perm order.
// Wm1T/bm1/Wm2/bm2 staged in 4.8KB LDS (same values, same fma order ->
// bit-identical) + unroll 4 for MLP on the serial j chain.
// ===========================================================================
__global__ __launch_bounds__(256) void edge_d_kernel(
    const float* __restrict__ x, const int4* __restrict__ edata,
    const float2* __restrict__ ewp,
    const float* __restrict__ Wm1T, const float* __restrict__ bm1,
    const float* __restrict__ Wm2, const float* __restrict__ bm2,
    const float* __restrict__ W2, const float* __restrict__ b2, bf16* __restrict__ msg)
{
    __shared__ float sw[C_MSG * 6 + 1];  // [0,800) Wm1T, [800,1000) bm1,
                                         // [1000,1200) Wm2, [1200] bm2
    for (int i = threadIdx.x; i < C_MSG * 6 + 1; i += 256) {
        float v;
        if (i < C_MSG * 4)            v = Wm1T[i];
        else if (i < C_MSG * 5)       v = bm1[i - C_MSG * 4];
        else if (i < C_MSG * 6)       v = Wm2[i - C_MSG * 5];
        else                          v = bm2[0];
        sw[i] = v;
    }
    __syncthreads();

    int t = blockIdx.x * 256 + threadIdx.x;
    int4 ed = edata[t];
    float xi = x[ed.y], xj = x[ed.x];
    float2 e01 = ewp[t];
    float e0 = e01.x, e1 = e01.y;
    float m = sw[C_MSG * 6];
#pragma unroll 4
    for (int j = 0; j < C_MSG; ++j) {
        const float* wr = sw + j * 4;
        float h = sw[C_MSG * 4 + j];
        h = fmaf(xi, wr[0], h);
        h = fmaf(xj, wr[1], h);
        h = fmaf(e0, wr[2], h);
        h = fmaf(e1, wr[3], h);
        h = fmaxf(h, 0.f);
        m = fmaf(h, sw[C_MSG * 5 + j], m);
    }
    float md = m * (xi - xj);
    for (int o = 0; o < 15; ++o) {
        float f0 = fmaf(md, W2[2 * o], b2[2 * o]);
        float f1 = fmaf(md, W2[2 * o + 1], b2[2 * o + 1]);
        *(unsigned int*)(msg + (size_t)t * 32 + 2 * o) = pk_bf16(f0, f1);
    }
}

// ===========================================================================
// MFMA edge kernel v21 == v17 (the 578-582us plateau config, bit-exact):
//  T=4 tiles/wave, Wm1+Wm2 staged in LDS (53248B, 3 blocks/CU),
//  launch_bounds(256,3), 2-deep gather prefetch.
//  R12 post-mortem: v20 (Wm2->global for 4 blocks/CU) REGRESSED 66->102us:
//  occupancy rose 26->38% but MfmaUtil FELL 24->16, FETCH 42->66MB, WRITE
//  50->94MB. Mechanism: the 14 global Wm2 loads/tile re-entered the
//  in-flight/vmcnt economy (v13's win was removing exactly this) and the
//  extra concurrent waves degraded L2 write-combining of msg. The latency
//  floor's concurrency term saturates at ~3 waves/SIMD — more waves just
//  contend for the same L2/in-flight resources.
//  Ledger (all measured): occupancy up = worse; T=8, setprio, XCD swizzle,
//  ewp, tail micro-opts = neutral; T=4 staging + LDS weights = the wins.
//  Floor arithmetic: ~2500cyc serial chain/tile x 4 tiles x 48.8 wave-
//  groups/SIMD / 3 concurrent ~= 65us/dispatch — matches measurement.
//  DO NOT: pair-outer chunk reuse (v15/v16 correctness hazard), Wm2->global
//  (v20 regression), T=8 (neutral), occupancy levers (saturated).
// ===========================================================================

#define LOAD_FRAGS(P, ED) do {                                                \
    const bf16* rd_ = xc + (size_t)(ED).y * 64 + quad * 8;                    \
    const bf16* rs_ = xc + (size_t)(ED).x * 64 + quad * 8;                    \
    P##A0 = *(const bf16x8*)(rd_);                                            \
    P##a2 = *(const bf16x8*)(rd_ + 32);                                       \
    P##A1 = *(const bf16x8*)(rs_);                                            \
    P##a3 = *(const bf16x8*)(rs_ + 32);                                       \
} while (0)

// Per-tile compute, v13 op order. Uses in-scope: Wm1L, Wm2L, cA, cB, cP,
// col, quad, row0, lane, SelB, W2B, msg, COUT.
#define COMPUTE_TILE(P, EDZ, EBASE) do {                                      \
    if (quad == 3) {                                                          \
        union { unsigned int u; bf16 b[2]; } cv_;                             \
        cv_.u = (unsigned int)(EDZ);                                          \
        P##A1[6] = cv_.b[0];                                                  \
        P##A1[7] = cv_.b[1];                                                  \
    }                                                                         \
    /* fused GEMM1/GEMM2: pair p_ -> chunk -> kt=p_ accumulation */           \
    f32x4 m0_ = {0.f,0.f,0.f,0.f}, m1_ = {0.f,0.f,0.f,0.f};                   \
    _Pragma("unroll")                                                         \
    for (int p_ = 0; p_ < 6; ++p_) {                                          \
        char* cb_ = (p_ & 1) ? cB : cA;                                       \
        const bf16* Wf_ = Wm1L + (4 * p_) * 512 + lane * 8;                   \
        bf16x8 be0_ = *(const bf16x8*)(Wf_);                                  \
        bf16x8 be1_ = *(const bf16x8*)(Wf_ + 512);                            \
        bf16x8 bo0_ = *(const bf16x8*)(Wf_ + 1024);                           \
        bf16x8 bo1_ = *(const bf16x8*)(Wf_ + 1536);                           \
        f32x4 ae_ = {0.f,0.f,0.f,0.f}, ao_ = {0.f,0.f,0.f,0.f};               \
        ae_ = MF(P##A0, be0_, ae_);                                           \
        ae_ = MF(P##A1, be1_, ae_);                                           \
        ao_ = MF(P##A0, bo0_, ao_);                                           \
        ao_ = MF(P##A1, bo1_, ao_);                                           \
        _Pragma("unroll")                                                     \
        for (int rg_ = 0; rg_ < 4; ++rg_) {                                   \
            int row_ = row0 + rg_, wb_ = 4 * col;                             \
            unsigned int u_ = pk_bf16(fmaxf(ae_[rg_],0.f), fmaxf(ao_[rg_],0.f)); \
            *(unsigned int*)(cb_ + row_ * 64 + ((wb_ & 48) ^ ((row_ & 3) << 4)) \
                             + (wb_ & 15)) = u_;                              \
        }                                                                     \
        bf16x8 a_ = *(const bf16x8*)(cb_ + col * 64 +                         \
                                     ((quad << 4) ^ ((col & 3) << 4)));       \
        m0_ = MF(a_, *(const bf16x8*)(Wm2L + p_ * 512 + lane * 8), m0_);      \
        m1_ = MF(a_, *(const bf16x8*)(Wm2L + (7 + p_) * 512 + lane * 8), m1_);\
    }                                                                         \
    {   /* leftover N-tile 12 (kt=6): cols 192..199 real, pad const in cP */  \
        const bf16* Wf_ = Wm1L + 24 * 512 + lane * 8;                         \
        bf16x8 b0_ = *(const bf16x8*)(Wf_);                                   \
        bf16x8 b1_ = *(const bf16x8*)(Wf_ + 512);                             \
        f32x4 acc_ = {0.f,0.f,0.f,0.f};                                       \
        acc_ = MF(P##A0, b0_, acc_);                                          \
        acc_ = MF(P##A1, b1_, acc_);                                          \
        if (col < 8) {                                                        \
            _Pragma("unroll")                                                 \
            for (int rg_ = 0; rg_ < 4; ++rg_) {                               \
                int row_ = row0 + rg_;                                        \
                *(bf16*)(cP + row_ * 64 + ((row_ & 3) << 4) + 2 * col) =      \
                    (bf16)fmaxf(acc_[rg_], 0.f);                              \
            }                                                                 \
        }                                                                     \
        bf16x8 a_ = *(const bf16x8*)(cP + col * 64 +                          \
                                     ((quad << 4) ^ ((col & 3) << 4)));       \
        m0_ = MF(a_, *(const bf16x8*)(Wm2L + 6 * 512 + lane * 8), m0_);       \
        m1_ = MF(a_, *(const bf16x8*)(Wm2L + 13 * 512 + lane * 8), m1_);      \
    }                                                                         \
    /* selector GEMM: diff[16x32] (rows 30/31 zero -> ew patch inert) */      \
    f32x4 dc0_ = {0.f,0.f,0.f,0.f}, dc1_ = {0.f,0.f,0.f,0.f};                 \
    dc0_ = MF(P##A0, *(const bf16x8*)(SelB + (size_t)0*512 + lane*8), dc0_);  \
    dc1_ = MF(P##A0, *(const bf16x8*)(SelB + (size_t)1*512 + lane*8), dc1_);  \
    dc0_ = MF(P##A1, *(const bf16x8*)(SelB + (size_t)2*512 + lane*8), dc0_);  \
    dc1_ = MF(P##A1, *(const bf16x8*)(SelB + (size_t)3*512 + lane*8), dc1_);  \
    dc0_ = MF(P##a2, *(const bf16x8*)(SelB + (size_t)4*512 + lane*8), dc0_);  \
    dc1_ = MF(P##a2, *(const bf16x8*)(SelB + (size_t)5*512 + lane*8), dc1_);  \
    dc0_ = MF(P##a3, *(const bf16x8*)(SelB + (size_t)6*512 + lane*8), dc0_);  \
    dc1_ = MF(P##a3, *(const bf16x8*)(SelB + (size_t)7*512 + lane*8), dc1_);  \
    /* md = m*diff -> chunkA -> GEMM3 A-frag */                               \
    _Pragma("unroll")                                                         \
    for (int rg_ = 0; rg_ < 4; ++rg_) {                                       \
        int row_ = row0 + rg_, wb_ = 4 * col;                                 \
        unsigned int u_ = (col == 15) ? pk_bf16(1.f, 0.f)                     \
                        : pk_bf16(m0_[rg_]*dc0_[rg_], m1_[rg_]*dc1_[rg_]);    \
        *(unsigned int*)(cA + row_ * 64 + ((wb_ & 48) ^ ((row_ & 3) << 4))    \
                         + (wb_ & 15)) = u_;                                  \
    }                                                                         \
    bf16x8 am_ = *(const bf16x8*)(cA + col * 64 +                             \
                                  ((quad << 4) ^ ((col & 3) << 4)));          \
    /* GEMM3: md[16x32] @ W2[32xN] -> msg */                                  \
    if (COUT == 30) {                                                         \
        f32x4 c0_ = {0.f,0.f,0.f,0.f}, c1_ = {0.f,0.f,0.f,0.f};               \
        c0_ = MF(am_, *(const bf16x8*)(W2B + lane*8), c0_);                   \
        c1_ = MF(am_, *(const bf16x8*)(W2B + 512 + lane*8), c1_);             \
        _Pragma("unroll")                                                     \
        for (int rg_ = 0; rg_ < 4; ++rg_)                                     \
            *(unsigned int*)(msg + (size_t)((EBASE) + row0 + rg_)*32 + 2*col) = \
                pk_bf16(c0_[rg_], c1_[rg_]);                                  \
    } else {                                                                  \
        /* COUT=1: compact msg1[e] — one 8B store per col==0 lane */          \
        f32x4 c0_ = {0.f,0.f,0.f,0.f};                                        \
        c0_ = MF(am_, *(const bf16x8*)(W2B + lane*8), c0_);                   \
        if (col == 0) {                                                       \
            union { bf16 h[4]; unsigned long long u; } pk4_;                  \
            _Pragma("unroll")                                                 \
            for (int rg_ = 0; rg_ < 4; ++rg_) pk4_.h[rg_] = (bf16)c0_[rg_];   \
            *(unsigned long long*)(msg + ((EBASE) + row0)) = pk4_.u;          \
        }                                                                     \
    }                                                                         \
} while (0)

template<int COUT>
__global__ __launch_bounds__(256, 3) void edge_mfma(
    const bf16* __restrict__ xc, const int4* __restrict__ edata,
    const bf16* __restrict__ Wm1B, const bf16* __restrict__ SelB,
    const bf16* __restrict__ Wm2B, const bf16* __restrict__ W2B,
    bf16* __restrict__ msg)
{
    // [0,13312): Wm1 26 frags; [13312,20480): Wm2 14 frags;
    // [20480,26624): 4 waves x 3 x 512 chunk buffers.  53248 B total.
    __shared__ __align__(16) bf16 smem[26624];
    bf16* Wm1L = smem;
    bf16* Wm2L = smem + 13312;

    const int tid = threadIdx.x, w = tid >> 6, lane = tid & 63;
    const int col = lane & 15, quad = lane >> 4, row0 = quad * 4;
    const int myrow = w * 16;
    const int blk = blockIdx.x * 256;             // 4 tiles x 64 edges

    // ---- issue all 4 edata loads FIRST (fly during staging) ----
    const int eoff = myrow + col;
    int4 ed0 = edata[blk + 0 * 64 + eoff];
    int4 ed1 = edata[blk + 1 * 64 + eoff];
    int4 ed2 = edata[blk + 2 * 64 + eoff];
    int4 ed3 = edata[blk + 3 * 64 + eoff];

    // ---- stage weights: 2560 x 16B chunks, 10 per thread ----
#pragma unroll
    for (int i = 0; i < 10; ++i) {
        int idx = tid + i * 256;
        bf16x8 v = (idx < 1664) ? *((const bf16x8*)Wm1B + idx)
                                : *((const bf16x8*)Wm2B + (idx - 1664));
        *((bf16x8*)smem + idx) = v;
    }
    __syncthreads();

    char* cbase = (char*)(smem + 20480 + w * 1536);
    char* cA = cbase;
    char* cB = cbase + 1024;
    char* cP = cbase + 2048;

    // cP pad slots 1..3 (global cols 200..223): slot1 elem0 = bm2 bias row
    // marker (1.0), rest 0. Written once; tiles only rewrite slot 0.
    if (lane < 48) {
        int r = lane / 3, s = 1 + (lane - r * 3);
        bf16x8 z = {};
        if (s == 1) z[0] = (bf16)1.f;
        *(bf16x8*)(cP + r * 64 + ((s << 4) ^ ((r & 3) << 4))) = z;
    }

    // ---- rolling 2-deep pipeline over 4 tiles ----
    bf16x8 pA0, pA1, pa2, pa3, qA0, qA1, qa2, qa3;
    LOAD_FRAGS(p, ed0);
    LOAD_FRAGS(q, ed1);

    COMPUTE_TILE(p, ed0.z, blk + 0 * 64 + myrow);
    LOAD_FRAGS(p, ed2);
    COMPUTE_TILE(q, ed1.z, blk + 1 * 64 + myrow);
    LOAD_FRAGS(q, ed3);
    COMPUTE_TILE(p, ed2.z, blk + 2 * 64 + myrow);
    COMPUTE_TILE(q, ed3.z, blk + 3 * 64 + myrow);
}

// ===========================================================================
// Fused aggregation + next node term. 16 lanes per node; width-16 shuffles;
// fma order identical to the original node_kernel -> numerically identical.
// j-loop unrolled 8 (adds still folded in ascending-j order -> bit-identical).
// ===========================================================================
template<int CNEXT>
__global__ __launch_bounds__(256) void agg_fused(
    const bf16* __restrict__ msg, const int* __restrict__ offsets,
    const float* __restrict__ bufc,
    const float* __restrict__ W1n, const float* __restrict__ b1n,
    float* __restrict__ bufn,
    bf16* __restrict__ xc) {
    int gh = (blockIdx.x * 256 + threadIdx.x) >> 4;
    int lane = threadIdx.x & 15;
    int s0 = offsets[gh], s1 = offsets[gh + 1];
    float r0 = 0.f, r1 = 0.f;
    if (lane < 15) {
        float v0 = 0.f, v1 = 0.f;
        const unsigned int* mp =
            (const unsigned int*)(msg + (size_t)s0 * 32 + lane * 2);
        int cnt = s1 - s0, j = 0;
        for (; j + 8 <= cnt; j += 8) {
            unsigned int u0 = mp[(size_t)(j + 0) * 16];
            unsigned int u1 = mp[(size_t)(j + 1) * 16];
            unsigned int u2 = mp[(size_t)(j + 2) * 16];
            unsigned int u3 = mp[(size_t)(j + 3) * 16];
            unsigned int u4 = mp[(size_t)(j + 4) * 16];
            unsigned int u5 = mp[(size_t)(j + 5) * 16];
            unsigned int u6 = mp[(size_t)(j + 6) * 16];
            unsigned int u7 = mp[(size_t)(j + 7) * 16];
            union { unsigned int u; bf16 b[2]; } c0, c1, c2, c3, c4, c5, c6, c7;
            c0.u = u0; c1.u = u1; c2.u = u2; c3.u = u3;
            c4.u = u4; c5.u = u5; c6.u = u6; c7.u = u7;
            v0 += (float)c0.b[0]; v1 += (float)c0.b[1];
            v0 += (float)c1.b[0]; v1 += (float)c1.b[1];
            v0 += (float)c2.b[0]; v1 += (float)c2.b[1];
            v0 += (float)c3.b[0]; v1 += (float)c3.b[1];
            v0 += (float)c4.b[0]; v1 += (float)c4.b[1];
            v0 += (float)c5.b[0]; v1 += (float)c5.b[1];
            v0 += (float)c6.b[0]; v1 += (float)c6.b[1];
            v0 += (float)c7.b[0]; v1 += (float)c7.b[1];
        }
        for (; j + 4 <= cnt; j += 4) {
            unsigned int u0 = mp[(size_t)(j + 0) * 16];
            unsigned int u1 = mp[(size_t)(j + 1) * 16];
            unsigned int u2 = mp[(size_t)(j + 2) * 16];
            unsigned int u3 = mp[(size_t)(j + 3) * 16];
            union { unsigned int u; bf16 b[2]; } c0, c1, c2, c3;
            c0.u = u0; c1.u = u1; c2.u = u2; c3.u = u3;
            v0 += (float)c0.b[0]; v1 += (float)c0.b[1];
            v0 += (float)c1.b[0]; v1 += (float)c1.b[1];
            v0 += (float)c2.b[0]; v1 += (float)c2.b[1];
            v0 += (float)c3.b[0]; v1 += (float)c3.b[1];
        }
        for (; j < cnt; ++j) {
            union { unsigned int u; bf16 b[2]; } cv;
            cv.u = mp[(size_t)j * 16];
            v0 += (float)cv.b[0]; v1 += (float)cv.b[1];
        }
        float f0 = bufc[(size_t)gh * 30 + 2 * lane] + v0;
        float f1 = bufc[(size_t)gh * 30 + 2 * lane + 1] + v1;
        r0 = fmaxf(f0, 0.f);
        r1 = fmaxf(f1, 0.f);
        bf16 h0 = (bf16)r0, h1 = (bf16)r1;
        union { bf16 h[2]; unsigned int u; } hi;
        hi.h[0] = h0; hi.h[1] = h1;
        *(unsigned int*)(xc + (size_t)gh * 64 + 2 * lane) = hi.u;
        *(unsigned int*)(xc + (size_t)gh * 64 + 32 + 2 * lane) =
            pk_bf16(r0 - (float)h0, r1 - (float)h1);
    } else {
        *(unsigned int*)(xc + (size_t)gh * 64 + 30) = pk_bf16(1.f, 0.f);
        *(unsigned int*)(xc + (size_t)gh * 64 + 62) = 0u;
    }
    // ---- next node term (fma order == original node_kernel) ----
    if (CNEXT == 30) {
        float acc0 = 0.f, acc1 = 0.f;
        if (lane < 15) { acc0 = b1n[2 * lane]; acc1 = b1n[2 * lane + 1]; }
        for (int k2 = 0; k2 < 15; ++k2) {
            float rk0 = __shfl(r0, k2, 16);
            float rk1 = __shfl(r1, k2, 16);
            if (lane < 15) {
                const float* w0 = W1n + (2 * k2) * 30 + 2 * lane;
                const float* w1 = W1n + (2 * k2 + 1) * 30 + 2 * lane;
                acc0 = fmaf(rk0, w0[0], acc0);
                acc1 = fmaf(rk0, w0[1], acc1);
                acc0 = fmaf(rk1, w1[0], acc0);
                acc1 = fmaf(rk1, w1[1], acc1);
            }
        }
        if (lane < 15) {
            bufn[(size_t)gh * 30 + 2 * lane] = acc0;
            bufn[(size_t)gh * 30 + 2 * lane + 1] = acc1;
        }
    } else {
        float acc = b1n[0];
        for (int k2 = 0; k2 < 15; ++k2) {
            float rk0 = __shfl(r0, k2, 16);
            float rk1 = __shfl(r1, k2, 16);
            acc = fmaf(rk0, W1n[2 * k2], acc);
            acc = fmaf(rk1, W1n[2 * k2 + 1], acc);
        }
        if (lane == 0) bufn[gh] = acc;
    }
}

// Final aggregation, compact msg1[e]: out[gh] += sum (same lane->j order)
__global__ __launch_bounds__(256) void agg_last(const bf16* __restrict__ msg1,
                                                const int* __restrict__ offsets,
                                                float* __restrict__ out) {
    int gh = (blockIdx.x * 256 + threadIdx.x) >> 5;
    int lane = threadIdx.x & 31;
    int s0 = offsets[gh], s1 = offsets[gh + 1];
    float v = 0.f;
    for (int j = s0 + lane; j < s1; j += 32) v += (float)msg1[j];
#pragma unroll
    for (int o = 16; o > 0; o >>= 1) v += __shfl_xor(v, o);
    if (lane == 0) out[gh] += v;
}

// ===========================================================================
extern "C" void kernel_launch(void* const* d_in, const int* in_sizes, int n_in,
                              void* d_out, int out_size, void* d_ws, size_t ws_size,
                              hipStream_t stream) {
    const float* features = (const float*)d_in[0];
    const int*   edges    = (const int*)d_in[1];
    const float* ew       = (const float*)d_in[2];

    const float* W1_d  = (const float*)d_in[3];
    const float* b1_d  = (const float*)d_in[4];
    const float* Wm1_d = (const float*)d_in[5];
    const float* bm1_d = (const float*)d_in[6];
    const float* Wm2_d = (const float*)d_in[7];
    const float* bm2_d = (const float*)d_in[8];
    const float* W2_d  = (const float*)d_in[9];
    const float* b2_d  = (const float*)d_in[10];

    const float* W1_h  = (const float*)d_in[11];
    const float* b1_h  = (const float*)d_in[12];
    const float* Wm1_h = (const float*)d_in[13];
    const float* bm1_h = (const float*)d_in[14];
    const float* Wm2_h = (const float*)d_in[15];
    const float* bm2_h = (const float*)d_in[16];
    const float* W2_h  = (const float*)d_in[17];
    const float* b2_h  = (const float*)d_in[18];

    const float* W1_o  = (const float*)d_in[19];
    const float* b1_o  = (const float*)d_in[20];
    const float* Wm1_o = (const float*)d_in[21];
    const float* bm1_o = (const float*)d_in[22];
    const float* Wm2_o = (const float*)d_in[23];
    const float* bm2_o = (const float*)d_in[24];
    const float* W2_o  = (const float*)d_in[25];
    const float* b2_o  = (const float*)d_in[26];

    const int* src = edges;
    const int* dst = edges + N_EDGES;
    float* out = (float*)d_out;

    // ---- workspace carve-up ----
    char* p = (char*)d_ws;
    auto alloc = [&](size_t bytes) { char* r = p; p += (bytes + 63) & ~(size_t)63; return r; };
    float* bufA    = (float*)alloc((size_t)N_NODES * 30 * 4);
    float* bufB    = (float*)alloc((size_t)N_NODES * 30 * 4);
    bf16*  msg     = (bf16*) alloc((size_t)N_EDGES * 32 * 2);
    bf16*  xc      = (bf16*) alloc((size_t)N_NODES * 64 * 2);
    int*   counts  = (int*)  alloc((size_t)N_NODES * 4);
    int*   offsets = (int*)  alloc((size_t)(N_NODES + 1) * 4);
    int*   cursor  = (int*)  alloc((size_t)N_NODES * 4);
    int4*  edata   = (int4*) alloc((size_t)N_EDGES * 16);
    float2* ewp    = (float2*)alloc((size_t)N_EDGES * 8);
    float* Wm1T_d  = (float*)alloc((size_t)C_MSG * 4 * 4);
    bf16*  Wm1B_h  = (bf16*) alloc((size_t)26 * 512 * 2);
    bf16*  Wm1B_o  = (bf16*) alloc((size_t)26 * 512 * 2);
    bf16*  Wm2B_h  = (bf16*) alloc((size_t)14 * 512 * 2);
    bf16*  Wm2B_o  = (bf16*) alloc((size_t)14 * 512 * 2);
    bf16*  W2B_h   = (bf16*) alloc((size_t)2 * 512 * 2);
    bf16*  W2B_o   = (bf16*) alloc((size_t)1 * 512 * 2);
    bf16*  SelB    = (bf16*) alloc((size_t)8 * 512 * 2);

    // ---- setup ----
    hipMemsetAsync(counts, 0, (size_t)N_NODES * 4, stream);
    setup_a<<<3507, 256, 0, stream>>>(dst, counts,
        Wm1_h, bm1_h, Wm1_o, bm1_o, Wm2_h, bm2_h, Wm2_o, bm2_o,
        W2_h, b2_h, W2_o, b2_o, Wm1_d,
        Wm1B_h, Wm1B_o, Wm2B_h, Wm2B_o, W2B_h, W2B_o, SelB, Wm1T_d,
        features, W1_d, b1_d, bufA);
    scan_kernel<<<(N_NODES + 255) / 256, 256, 0, stream>>>(counts, offsets, cursor);
    scatter_kernel<<<N_EDGES / 256, 256, 0, stream>>>(src, dst, ew, cursor, edata, ewp);

    dim3 tb(256);
    dim3 eb_mfma(N_EDGES / 256);   // 4 tiles of 64 edges per block
    dim3 eb_valu(N_EDGES / 256);
    dim3 ab16(N_NODES * 16 / 256);
    dim3 ab32(N_NODES * 32 / 256);

    // ---- layer d ----
    edge_d_kernel<<<eb_valu, tb, 0, stream>>>(features, edata, ewp,
        Wm1T_d, bm1_d, Wm2_d, bm2_d, W2_d, b2_d, msg);
    agg_fused<30><<<ab16, tb, 0, stream>>>(msg, offsets, bufA, W1_h, b1_h, bufB, xc);

    // ---- h1 ----
    edge_mfma<30><<<eb_mfma, tb, 0, stream>>>(xc, edata,
        Wm1B_h, SelB, Wm2B_h, W2B_h, msg);
    agg_fused<30><<<ab16, tb, 0, stream>>>(msg, offsets, bufB, W1_h, b1_h, bufA, xc);

    // ---- h2 ----
    edge_mfma<30><<<eb_mfma, tb, 0, stream>>>(xc, edata,
        Wm1B_h, SelB, Wm2B_h, W2B_h, msg);
    agg_fused<30><<<ab16, tb, 0, stream>>>(msg, offsets, bufA, W1_h, b1_h, bufB, xc);

    // ---- h3 (next node term = output layer -> writes d_out) ----
    edge_mfma<30><<<eb_mfma, tb, 0, stream>>>(xc, edata,
        Wm1B_h, SelB, Wm2B_h, W2B_h, msg);
    agg_fused<1><<<ab16, tb, 0, stream>>>(msg, offsets, bufB, W1_o, b1_o, out, xc);

    // ---- output layer (compact msg1) ----
    edge_mfma<1><<<eb_mfma, tb, 0, stream>>>(xc, edata,
        Wm1B_o, SelB, Wm2B_o, W2B_o, msg);
    agg_last<<<ab32, tb, 0, stream>>>(msg, offsets, out);
}